// Round 1
// baseline (478.258 us; speedup 1.0000x reference)
//
#include <hip/hip_runtime.h>
#include <hip/hip_bf16.h>

typedef __attribute__((ext_vector_type(8))) short short8;
typedef __attribute__((ext_vector_type(4))) float f32x4;

#define BN_EPS 1e-5f

// ---------- bf16 helpers (RNE) ----------
__device__ __forceinline__ float bf2f(unsigned short u) {
    unsigned int x = ((unsigned int)u) << 16;
    union { unsigned int i; float f; } c; c.i = x; return c.f;
}
__device__ __forceinline__ unsigned short f2bf(float f) {
    union { float f; unsigned int i; } c; c.f = f;
    unsigned int lsb = (c.i >> 16) & 1u;
    c.i += 0x7fffu + lsb;
    return (unsigned short)(c.i >> 16);
}

// ---------- async global->LDS 16B ----------
typedef const unsigned int __attribute__((address_space(1)))* gas_t;
typedef unsigned int __attribute__((address_space(3)))* las_t;
__device__ __forceinline__ void gload_lds16(const void* src, void* ldsdst) {
    __builtin_amdgcn_global_load_lds((gas_t)src, (las_t)ldsdst, 16, 0, 0);
}

// ---------- convert weights to bf16 ----------
__global__ __launch_bounds__(256) void k_convert(const float* __restrict__ W1,
        const float* __restrict__ W2, unsigned short* __restrict__ W1b,
        unsigned short* __restrict__ W2b) {
    int i = blockIdx.x * 256 + threadIdx.x;
    if (i < 256 * 384) W1b[i] = f2bf(W1[i]);
    if (i < 256 * 256) W2b[i] = f2bf(W2[i]);
}

// ---------- 3-NN + weights ----------
__global__ __launch_bounds__(256) void k_knn(const float* __restrict__ xyz1,
        const float* __restrict__ xyz2, int* __restrict__ idx3, float* __restrict__ w3) {
    __shared__ float sx[1024], sy[1024], sz[1024], sn[1024];
    int b = blockIdx.x >> 4;
    int n0 = (blockIdx.x & 15) * 256;
    const float* x2 = xyz2 + (size_t)b * 3 * 1024;
    for (int i = threadIdx.x; i < 1024; i += 256) {
        float a = x2[i], c = x2[1024 + i], d = x2[2048 + i];
        sx[i] = a; sy[i] = c; sz[i] = d; sn[i] = a * a + c * c + d * d;
    }
    __syncthreads();
    int n = n0 + threadIdx.x;
    const float* x1 = xyz1 + (size_t)b * 3 * 4096;
    float px = x1[n], py = x1[4096 + n], pz = x1[8192 + n];
    float s1 = px * px + py * py + pz * pz;
    float d0 = 1e30f, d1 = 1e30f, d2 = 1e30f;
    int i0 = 0, i1 = 0, i2 = 0;
    for (int j = 0; j < 1024; ++j) {
        float dot = px * sx[j] + py * sy[j] + pz * sz[j];
        float d = -2.0f * dot; d += s1; d += sn[j];
        if (d < d2) {
            if (d < d1) {
                d2 = d1; i2 = i1;
                if (d < d0) { d1 = d0; i1 = i0; d0 = d; i0 = j; }
                else { d1 = d; i1 = j; }
            } else { d2 = d; i2 = j; }
        }
    }
    d0 = fmaxf(d0, 1e-10f); d1 = fmaxf(d1, 1e-10f); d2 = fmaxf(d2, 1e-10f);
    float w0 = 1.f / d0, w1 = 1.f / d1, w2 = 1.f / d2;
    float s = w0 + w1 + w2; w0 /= s; w1 /= s; w2 /= s;
    size_t base = ((size_t)b * 4096 + n) * 3;
    idx3[base] = i0; idx3[base + 1] = i1; idx3[base + 2] = i2;
    w3[base] = w0; w3[base + 1] = w1; w3[base + 2] = w2;
}

// ---------- build Xt[b*4096+n][384] = concat(points1^T, interp) in bf16 ----------
__global__ __launch_bounds__(256) void k_build(const float* __restrict__ p1,
        const float* __restrict__ p2, const int* __restrict__ idx3,
        const float* __restrict__ w3, unsigned short* __restrict__ Xt) {
    __shared__ float tile[64][65];
    __shared__ int sidx[64][3];
    __shared__ float sw[64][3];
    int b = blockIdx.y;
    int n0 = blockIdx.x * 64;
    int t = threadIdx.x;
    if (t < 192) {
        size_t base = ((size_t)b * 4096 + n0) * 3;
        ((int*)sidx)[t] = idx3[base + t];
        ((float*)sw)[t] = w3[base + t];
    }
    const float* p1b = p1 + (size_t)b * 128 * 4096 + n0;
    unsigned short* Xb = Xt + ((size_t)b * 4096 + n0) * 384;
    for (int c0 = 0; c0 < 128; c0 += 64) {
        __syncthreads();
        #pragma unroll
        for (int i = 0; i < 16; ++i) {
            int e = i * 256 + t;
            int c = e >> 6, nn = e & 63;
            tile[c][nn] = p1b[(size_t)(c0 + c) * 4096 + nn];
        }
        __syncthreads();
        int nn = t >> 2, cs = (t & 3) * 16;
        unsigned short* dst = Xb + (size_t)nn * 384 + c0 + cs;
        #pragma unroll
        for (int i = 0; i < 16; ++i) dst[i] = f2bf(tile[cs + i][nn]);
    }
    __syncthreads();
    const float* pr = p2 + (size_t)b * 256 * 1024 + (size_t)t * 1024;
    for (int nn = 0; nn < 64; ++nn) {
        float v = sw[nn][0] * pr[sidx[nn][0]] + sw[nn][1] * pr[sidx[nn][1]]
                + sw[nn][2] * pr[sidx[nn][2]];
        Xb[(size_t)nn * 384 + 128 + t] = f2bf(v);
    }
}

// ---------- GEMM: C[ar][bc] = sum_k A[ar][k]*B[bc][k], A,B row-major [rows][Kdim] bf16 ----------
// out index = arow*sA + (brow>>12)*sBatch + (brow&4095)
__global__ __launch_bounds__(256) void k_gemm(const unsigned short* __restrict__ A,
        const unsigned short* __restrict__ B, unsigned short* __restrict__ C,
        int Kdim, size_t sA, size_t sBatch) {
    __shared__ unsigned short lA[128 * 32];
    __shared__ unsigned short lB[128 * 32];
    int t = threadIdx.x;
    int w = t >> 6, lane = t & 63;
    int ar0 = blockIdx.x * 128, br0 = blockIdx.y * 128;
    int war = (w >> 1) * 64, wbr = (w & 1) * 64;
    f32x4 acc[4][4] = {};
    int rlo = lane & 15, khi = lane >> 4;
    for (int kk = 0; kk < Kdim; kk += 32) {
        #pragma unroll
        for (int it = 0; it < 2; ++it) {
            int q = it * 256 + w * 64 + lane;
            int row = q >> 2, kc = q & 3;
            const unsigned short* srcA = A + (size_t)(ar0 + row) * Kdim + kk + ((kc ^ (row & 3)) << 3);
            gload_lds16(srcA, &lA[(size_t)(it * 256 + w * 64) * 8]);
            const unsigned short* srcB = B + (size_t)(br0 + row) * Kdim + kk + ((kc ^ (row & 3)) << 3);
            gload_lds16(srcB, &lB[(size_t)(it * 256 + w * 64) * 8]);
        }
        __syncthreads();
        short8 af[4], bfr[4];
        #pragma unroll
        for (int mi = 0; mi < 4; ++mi) {
            int r = war + mi * 16 + rlo;
            af[mi] = *(const short8*)&lA[(size_t)(r * 4 + (khi ^ (r & 3))) * 8];
        }
        #pragma unroll
        for (int ni = 0; ni < 4; ++ni) {
            int r = wbr + ni * 16 + rlo;
            bfr[ni] = *(const short8*)&lB[(size_t)(r * 4 + (khi ^ (r & 3))) * 8];
        }
        #pragma unroll
        for (int mi = 0; mi < 4; ++mi)
            #pragma unroll
            for (int ni = 0; ni < 4; ++ni)
                acc[mi][ni] = __builtin_amdgcn_mfma_f32_16x16x32_bf16(af[mi], bfr[ni], acc[mi][ni], 0, 0, 0);
        __syncthreads();
    }
    #pragma unroll
    for (int mi = 0; mi < 4; ++mi) {
        #pragma unroll
        for (int ni = 0; ni < 4; ++ni) {
            #pragma unroll
            for (int r = 0; r < 4; ++r) {
                int arow = ar0 + war + mi * 16 + khi * 4 + r;
                int brow = br0 + wbr + ni * 16 + rlo;
                size_t oidx = (size_t)arow * sA + (size_t)(brow >> 12) * sBatch + (size_t)(brow & 4095);
                C[oidx] = f2bf(acc[mi][ni][r]);
            }
        }
    }
}

// ---------- BN stats stage 1 over h1 [65536][256] ----------
__global__ __launch_bounds__(256) void k_stats1(const unsigned short* __restrict__ h1,
        float* __restrict__ ps, float* __restrict__ pq) {
    int c = threadIdx.x;
    size_t r0 = (size_t)blockIdx.x * 256;
    float s = 0.f, q = 0.f;
    for (int i = 0; i < 256; ++i) {
        float v = bf2f(h1[(r0 + i) * 256 + c]);
        s += v; q += v * v;
    }
    ps[blockIdx.x * 256 + c] = s;
    pq[blockIdx.x * 256 + c] = q;
}

__global__ __launch_bounds__(256) void k_fin1(const float* __restrict__ ps,
        const float* __restrict__ pq, const float* __restrict__ g,
        const float* __restrict__ be, float* __restrict__ av, float* __restrict__ bv) {
    int c = threadIdx.x;
    float s = 0.f, q = 0.f;
    for (int i = 0; i < 256; ++i) { s += ps[i * 256 + c]; q += pq[i * 256 + c]; }
    float mean = s / 65536.0f;
    float var = q / 65536.0f - mean * mean;
    float a = g[c] * rsqrtf(var + BN_EPS);
    av[c] = a; bv[c] = be[c] - mean * a;
}

// ---------- normalize+relu h1 in place ----------
__global__ __launch_bounds__(256) void k_norm1(unsigned short* __restrict__ h1,
        const float* __restrict__ av, const float* __restrict__ bv) {
    size_t i0 = ((size_t)blockIdx.x * 256 + threadIdx.x) * 8;
    int c0 = (int)(i0 & 255);
    short8 v = *(short8*)&h1[i0];
    short8 o;
    #pragma unroll
    for (int j = 0; j < 8; ++j) {
        float x = bf2f((unsigned short)v[j]);
        float y = av[c0 + j] * x + bv[c0 + j];
        o[j] = (short)f2bf(fmaxf(y, 0.f));
    }
    *(short8*)&h1[i0] = o;
}

// ---------- BN stats over h2 [16][256][4096]: one block per (b,o) row ----------
__global__ __launch_bounds__(256) void k_stats2(const unsigned short* __restrict__ h2,
        float* __restrict__ ps, float* __restrict__ pq) {
    size_t row = blockIdx.x;
    const unsigned short* p = h2 + row * 4096;
    int t = threadIdx.x;
    float s = 0.f, q = 0.f;
    #pragma unroll
    for (int j = 0; j < 2; ++j) {
        short8 v = *(const short8*)&p[t * 16 + j * 8];
        #pragma unroll
        for (int e = 0; e < 8; ++e) {
            float x = bf2f((unsigned short)v[e]);
            s += x; q += x * x;
        }
    }
    #pragma unroll
    for (int off = 32; off; off >>= 1) { s += __shfl_down(s, off); q += __shfl_down(q, off); }
    __shared__ float ss[4], sq[4];
    if ((t & 63) == 0) { ss[t >> 6] = s; sq[t >> 6] = q; }
    __syncthreads();
    if (t == 0) {
        ps[row] = ss[0] + ss[1] + ss[2] + ss[3];
        pq[row] = sq[0] + sq[1] + sq[2] + sq[3];
    }
}

__global__ __launch_bounds__(256) void k_fin2(const float* __restrict__ ps,
        const float* __restrict__ pq, const float* __restrict__ g,
        const float* __restrict__ be, float* __restrict__ av, float* __restrict__ bv) {
    int o = threadIdx.x;
    float s = 0.f, q = 0.f;
    for (int b = 0; b < 16; ++b) { s += ps[b * 256 + o]; q += pq[b * 256 + o]; }
    float mean = s / 65536.0f;
    float var = q / 65536.0f - mean * mean;
    float a = g[o] * rsqrtf(var + BN_EPS);
    av[o] = a; bv[o] = be[o] - mean * a;
}

// ---------- final normalize+relu -> f32 out ----------
__global__ __launch_bounds__(256) void k_final(const unsigned short* __restrict__ h2,
        const float* __restrict__ av, const float* __restrict__ bv, float* __restrict__ out) {
    size_t i0 = ((size_t)blockIdx.x * 256 + threadIdx.x) * 8;
    int o = (int)((i0 >> 12) & 255);
    float a = av[o], b = bv[o];
    short8 v = *(const short8*)&h2[i0];
    f32x4 r0, r1;
    #pragma unroll
    for (int j = 0; j < 4; ++j) r0[j] = fmaxf(a * bf2f((unsigned short)v[j]) + b, 0.f);
    #pragma unroll
    for (int j = 0; j < 4; ++j) r1[j] = fmaxf(a * bf2f((unsigned short)v[4 + j]) + b, 0.f);
    *(f32x4*)&out[i0] = r0;
    *(f32x4*)&out[i0 + 4] = r1;
}

extern "C" void kernel_launch(void* const* d_in, const int* in_sizes, int n_in,
                              void* d_out, int out_size, void* d_ws, size_t ws_size,
                              hipStream_t stream) {
    const float* xyz1 = (const float*)d_in[0];
    const float* xyz2 = (const float*)d_in[1];
    const float* p1   = (const float*)d_in[2];
    const float* p2   = (const float*)d_in[3];
    const float* W1   = (const float*)d_in[4];
    const float* g1   = (const float*)d_in[5];
    const float* be1  = (const float*)d_in[6];
    const float* W2   = (const float*)d_in[7];
    const float* g2   = (const float*)d_in[8];
    const float* be2  = (const float*)d_in[9];
    float* out = (float*)d_out;
    char* ws = (char*)d_ws;

    unsigned short* Xt  = (unsigned short*)(ws);                    // 50,331,648 B
    unsigned short* h1  = (unsigned short*)(ws + 50331648);         // 33,554,432 B
    unsigned short* h2  = (unsigned short*)(ws + 83886080);         // 33,554,432 B
    unsigned short* W1b = (unsigned short*)(ws + 117440512);        // 196,608 B
    unsigned short* W2b = (unsigned short*)(ws + 117637120);        // 131,072 B
    int*   idx3 = (int*)(ws + 117768192);                           // 786,432 B
    float* w3   = (float*)(ws + 118554624);                         // 786,432 B
    float* ps1  = (float*)(ws + 119341056);                         // 262,144 B
    float* pq1  = (float*)(ws + 119603200);                         // 262,144 B
    float* ps2  = (float*)(ws + 119865344);                         // 16,384 B
    float* pq2  = (float*)(ws + 119881728);                         // 16,384 B
    float* a1v  = (float*)(ws + 119898112);
    float* b1v  = (float*)(ws + 119899136);
    float* a2v  = (float*)(ws + 119900160);
    float* b2v  = (float*)(ws + 119901184);

    k_convert<<<dim3(384), dim3(256), 0, stream>>>(W1, W2, W1b, W2b);
    k_knn<<<dim3(256), dim3(256), 0, stream>>>(xyz1, xyz2, idx3, w3);
    k_build<<<dim3(64, 16), dim3(256), 0, stream>>>(p1, p2, idx3, w3, Xt);
    // GEMM1: A = Xt (65536 x 384), B = W1b (256 x 384) -> h1[n][o]
    k_gemm<<<dim3(512, 2), dim3(256), 0, stream>>>(Xt, W1b, h1, 384, 256, 0);
    k_stats1<<<dim3(256), dim3(256), 0, stream>>>(h1, ps1, pq1);
    k_fin1<<<dim3(1), dim3(256), 0, stream>>>(ps1, pq1, g1, be1, a1v, b1v);
    k_norm1<<<dim3(8192), dim3(256), 0, stream>>>(h1, a1v, b1v);
    // GEMM2: A = W2b (256 x 256), B = h1 (65536 x 256) -> h2[b][o][n]
    k_gemm<<<dim3(2, 512), dim3(256), 0, stream>>>(W2b, h1, h2, 256, 4096, 1048576);
    k_stats2<<<dim3(4096), dim3(256), 0, stream>>>(h2, ps2, pq2);
    k_fin2<<<dim3(1), dim3(256), 0, stream>>>(ps2, pq2, g2, be2, a2v, b2v);
    k_final<<<dim3(8192), dim3(256), 0, stream>>>(h2, a2v, b2v, out);
}

// Round 2
// 277.587 us; speedup vs baseline: 1.7229x; 1.7229x over previous
//
#include <hip/hip_runtime.h>
#include <hip/hip_bf16.h>

typedef __attribute__((ext_vector_type(8))) short short8;
typedef __attribute__((ext_vector_type(4))) float f32x4;

#define BN_EPS 1e-5f

// ---------- bf16 helpers (RNE) ----------
__device__ __forceinline__ float bf2f(unsigned short u) {
    unsigned int x = ((unsigned int)u) << 16;
    union { unsigned int i; float f; } c; c.i = x; return c.f;
}
__device__ __forceinline__ unsigned short f2bf(float f) {
    union { float f; unsigned int i; } c; c.f = f;
    unsigned int lsb = (c.i >> 16) & 1u;
    c.i += 0x7fffu + lsb;
    return (unsigned short)(c.i >> 16);
}

// ---------- async global->LDS 16B ----------
typedef const unsigned int __attribute__((address_space(1)))* gas_t;
typedef unsigned int __attribute__((address_space(3)))* las_t;
__device__ __forceinline__ void gload_lds16(const void* src, void* ldsdst) {
    __builtin_amdgcn_global_load_lds((gas_t)src, (las_t)ldsdst, 16, 0, 0);
}

// ---------- convert weights to bf16 ----------
__global__ __launch_bounds__(256) void k_convert(const float* __restrict__ W1,
        const float* __restrict__ W2, unsigned short* __restrict__ W1b,
        unsigned short* __restrict__ W2b) {
    int i = blockIdx.x * 256 + threadIdx.x;
    if (i < 256 * 384) W1b[i] = f2bf(W1[i]);
    if (i < 256 * 256) W2b[i] = f2bf(W2[i]);
}

// ---------- 3-NN + weights ----------
__global__ __launch_bounds__(256) void k_knn(const float* __restrict__ xyz1,
        const float* __restrict__ xyz2, int* __restrict__ idx3, float* __restrict__ w3) {
    __shared__ float sx[1024], sy[1024], sz[1024], sn[1024];
    int b = blockIdx.x >> 4;
    int n0 = (blockIdx.x & 15) * 256;
    const float* x2 = xyz2 + (size_t)b * 3 * 1024;
    for (int i = threadIdx.x; i < 1024; i += 256) {
        float a = x2[i], c = x2[1024 + i], d = x2[2048 + i];
        sx[i] = a; sy[i] = c; sz[i] = d; sn[i] = a * a + c * c + d * d;
    }
    __syncthreads();
    int n = n0 + threadIdx.x;
    const float* x1 = xyz1 + (size_t)b * 3 * 4096;
    float px = x1[n], py = x1[4096 + n], pz = x1[8192 + n];
    float s1 = px * px + py * py + pz * pz;
    float d0 = 1e30f, d1 = 1e30f, d2 = 1e30f;
    int i0 = 0, i1 = 0, i2 = 0;
    for (int j = 0; j < 1024; ++j) {
        float dot = px * sx[j] + py * sy[j] + pz * sz[j];
        float d = -2.0f * dot; d += s1; d += sn[j];
        if (d < d2) {
            if (d < d1) {
                d2 = d1; i2 = i1;
                if (d < d0) { d1 = d0; i1 = i0; d0 = d; i0 = j; }
                else { d1 = d; i1 = j; }
            } else { d2 = d; i2 = j; }
        }
    }
    d0 = fmaxf(d0, 1e-10f); d1 = fmaxf(d1, 1e-10f); d2 = fmaxf(d2, 1e-10f);
    float w0 = 1.f / d0, w1 = 1.f / d1, w2 = 1.f / d2;
    float s = w0 + w1 + w2; w0 /= s; w1 /= s; w2 /= s;
    size_t base = ((size_t)b * 4096 + n) * 3;
    idx3[base] = i0; idx3[base + 1] = i1; idx3[base + 2] = i2;
    w3[base] = w0; w3[base + 1] = w1; w3[base + 2] = w2;
}

// ---------- transpose p2 [b][256][1024] f32 -> p2t [b][1024][256] bf16 ----------
__global__ __launch_bounds__(256) void k_tr_p2(const float* __restrict__ p2,
        unsigned short* __restrict__ p2t) {
    __shared__ float tile[64][65];
    int b = blockIdx.y;
    int n0 = (blockIdx.x & 15) * 64;
    int c0 = (blockIdx.x >> 4) * 64;
    int t = threadIdx.x;
    const float* src = p2 + (size_t)b * 256 * 1024 + (size_t)c0 * 1024 + n0;
    #pragma unroll
    for (int i = 0; i < 16; ++i) {
        int e = i * 256 + t;
        int c = e >> 6, n = e & 63;
        tile[c][n] = src[(size_t)c * 1024 + n];
    }
    __syncthreads();
    int n = t >> 2, cs = (t & 3) * 16;
    unsigned short* dst = p2t + ((size_t)b * 1024 + n0 + n) * 256 + c0 + cs;
    short8 o0, o1;
    #pragma unroll
    for (int i = 0; i < 8; ++i) o0[i] = (short)f2bf(tile[cs + i][n]);
    #pragma unroll
    for (int i = 0; i < 8; ++i) o1[i] = (short)f2bf(tile[cs + 8 + i][n]);
    *(short8*)dst = o0;
    *(short8*)(dst + 8) = o1;
}

// ---------- build Xt[b*4096+n][384] = concat(points1^T, interp) in bf16 ----------
__global__ __launch_bounds__(256) void k_build(const float* __restrict__ p1,
        const unsigned short* __restrict__ p2t, const int* __restrict__ idx3,
        const float* __restrict__ w3, unsigned short* __restrict__ Xt) {
    __shared__ float tile[64][65];
    __shared__ int sidx[64][3];
    __shared__ float sw[64][3];
    int b = blockIdx.y;
    int n0 = blockIdx.x * 64;
    int t = threadIdx.x;
    if (t < 192) {
        size_t base = ((size_t)b * 4096 + n0) * 3;
        ((int*)sidx)[t] = idx3[base + t];
        ((float*)sw)[t] = w3[base + t];
    }
    const float* p1b = p1 + (size_t)b * 128 * 4096 + n0;
    unsigned short* Xb = Xt + ((size_t)b * 4096 + n0) * 384;
    // part A: transpose p1 (c = 0..127)
    for (int c0 = 0; c0 < 128; c0 += 64) {
        __syncthreads();
        #pragma unroll
        for (int i = 0; i < 16; ++i) {
            int e = i * 256 + t;
            int c = e >> 6, nn = e & 63;
            tile[c][nn] = p1b[(size_t)(c0 + c) * 4096 + nn];
        }
        __syncthreads();
        int nn = t >> 2, cs = (t & 3) * 16;
        unsigned short* dst = Xb + (size_t)nn * 384 + c0 + cs;
        short8 o0, o1;
        #pragma unroll
        for (int i = 0; i < 8; ++i) o0[i] = (short)f2bf(tile[cs + i][nn]);
        #pragma unroll
        for (int i = 0; i < 8; ++i) o1[i] = (short)f2bf(tile[cs + 8 + i][nn]);
        *(short8*)dst = o0;
        *(short8*)(dst + 8) = o1;
    }
    // part B: interpolation (c = 128..383), 4 lanes per point, 64 ch each
    {
        int nn = t >> 2, cs = (t & 3) * 64;
        const unsigned short* pb = p2t + (size_t)b * 1024 * 256 + cs;
        const unsigned short* r0 = pb + (size_t)sidx[nn][0] * 256;
        const unsigned short* r1 = pb + (size_t)sidx[nn][1] * 256;
        const unsigned short* r2 = pb + (size_t)sidx[nn][2] * 256;
        float w0 = sw[nn][0], w1 = sw[nn][1], w2 = sw[nn][2];
        unsigned short* dst = Xb + (size_t)nn * 384 + 128 + cs;
        #pragma unroll
        for (int j = 0; j < 8; ++j) {
            short8 a = *(const short8*)(r0 + j * 8);
            short8 bb = *(const short8*)(r1 + j * 8);
            short8 cc = *(const short8*)(r2 + j * 8);
            short8 o;
            #pragma unroll
            for (int e = 0; e < 8; ++e) {
                float v = w0 * bf2f((unsigned short)a[e]) + w1 * bf2f((unsigned short)bb[e])
                        + w2 * bf2f((unsigned short)cc[e]);
                o[e] = (short)f2bf(v);
            }
            *(short8*)(dst + j * 8) = o;
        }
    }
}

// ---------- GEMM: C[ar][bc] = sum_k A[ar][k]*B[bc][k], A,B row-major [rows][Kdim] bf16 ----------
// out index = arow*sA + (brow>>12)*sBatch + (brow&4095)
__global__ __launch_bounds__(256) void k_gemm(const unsigned short* __restrict__ A,
        const unsigned short* __restrict__ B, unsigned short* __restrict__ C,
        int Kdim, size_t sA, size_t sBatch) {
    __shared__ unsigned short lA[128 * 32];
    __shared__ unsigned short lB[128 * 32];
    int t = threadIdx.x;
    int w = t >> 6, lane = t & 63;
    int ar0 = blockIdx.x * 128, br0 = blockIdx.y * 128;
    int war = (w >> 1) * 64, wbr = (w & 1) * 64;
    f32x4 acc[4][4] = {};
    int rlo = lane & 15, khi = lane >> 4;
    for (int kk = 0; kk < Kdim; kk += 32) {
        #pragma unroll
        for (int it = 0; it < 2; ++it) {
            int q = it * 256 + w * 64 + lane;
            int row = q >> 2, kc = q & 3;
            const unsigned short* srcA = A + (size_t)(ar0 + row) * Kdim + kk + ((kc ^ (row & 3)) << 3);
            gload_lds16(srcA, &lA[(size_t)(it * 256 + w * 64) * 8]);
            const unsigned short* srcB = B + (size_t)(br0 + row) * Kdim + kk + ((kc ^ (row & 3)) << 3);
            gload_lds16(srcB, &lB[(size_t)(it * 256 + w * 64) * 8]);
        }
        __syncthreads();
        short8 af[4], bfr[4];
        #pragma unroll
        for (int mi = 0; mi < 4; ++mi) {
            int r = war + mi * 16 + rlo;
            af[mi] = *(const short8*)&lA[(size_t)(r * 4 + (khi ^ (r & 3))) * 8];
        }
        #pragma unroll
        for (int ni = 0; ni < 4; ++ni) {
            int r = wbr + ni * 16 + rlo;
            bfr[ni] = *(const short8*)&lB[(size_t)(r * 4 + (khi ^ (r & 3))) * 8];
        }
        #pragma unroll
        for (int mi = 0; mi < 4; ++mi)
            #pragma unroll
            for (int ni = 0; ni < 4; ++ni)
                acc[mi][ni] = __builtin_amdgcn_mfma_f32_16x16x32_bf16(af[mi], bfr[ni], acc[mi][ni], 0, 0, 0);
        __syncthreads();
    }
    #pragma unroll
    for (int mi = 0; mi < 4; ++mi) {
        #pragma unroll
        for (int ni = 0; ni < 4; ++ni) {
            #pragma unroll
            for (int r = 0; r < 4; ++r) {
                int arow = ar0 + war + mi * 16 + khi * 4 + r;
                int brow = br0 + wbr + ni * 16 + rlo;
                size_t oidx = (size_t)arow * sA + (size_t)(brow >> 12) * sBatch + (size_t)(brow & 4095);
                C[oidx] = f2bf(acc[mi][ni][r]);
            }
        }
    }
}

// ---------- BN stats stage 1 over h1 [65536][256] ----------
__global__ __launch_bounds__(256) void k_stats1(const unsigned short* __restrict__ h1,
        float* __restrict__ ps, float* __restrict__ pq) {
    int c = threadIdx.x;
    size_t r0 = (size_t)blockIdx.x * 256;
    float s = 0.f, q = 0.f;
    for (int i = 0; i < 256; ++i) {
        float v = bf2f(h1[(r0 + i) * 256 + c]);
        s += v; q += v * v;
    }
    ps[blockIdx.x * 256 + c] = s;
    pq[blockIdx.x * 256 + c] = q;
}

__global__ __launch_bounds__(256) void k_fin1(const float* __restrict__ ps,
        const float* __restrict__ pq, const float* __restrict__ g,
        const float* __restrict__ be, float* __restrict__ av, float* __restrict__ bv) {
    int c = threadIdx.x;
    float s = 0.f, q = 0.f;
    for (int i = 0; i < 256; ++i) { s += ps[i * 256 + c]; q += pq[i * 256 + c]; }
    float mean = s / 65536.0f;
    float var = q / 65536.0f - mean * mean;
    float a = g[c] * rsqrtf(var + BN_EPS);
    av[c] = a; bv[c] = be[c] - mean * a;
}

// ---------- normalize+relu h1 in place ----------
__global__ __launch_bounds__(256) void k_norm1(unsigned short* __restrict__ h1,
        const float* __restrict__ av, const float* __restrict__ bv) {
    size_t i0 = ((size_t)blockIdx.x * 256 + threadIdx.x) * 8;
    int c0 = (int)(i0 & 255);
    short8 v = *(short8*)&h1[i0];
    short8 o;
    #pragma unroll
    for (int j = 0; j < 8; ++j) {
        float x = bf2f((unsigned short)v[j]);
        float y = av[c0 + j] * x + bv[c0 + j];
        o[j] = (short)f2bf(fmaxf(y, 0.f));
    }
    *(short8*)&h1[i0] = o;
}

// ---------- BN stats over h2 [16][256][4096]: one block per (b,o) row ----------
__global__ __launch_bounds__(256) void k_stats2(const unsigned short* __restrict__ h2,
        float* __restrict__ ps, float* __restrict__ pq) {
    size_t row = blockIdx.x;
    const unsigned short* p = h2 + row * 4096;
    int t = threadIdx.x;
    float s = 0.f, q = 0.f;
    #pragma unroll
    for (int j = 0; j < 2; ++j) {
        short8 v = *(const short8*)&p[t * 16 + j * 8];
        #pragma unroll
        for (int e = 0; e < 8; ++e) {
            float x = bf2f((unsigned short)v[e]);
            s += x; q += x * x;
        }
    }
    #pragma unroll
    for (int off = 32; off; off >>= 1) { s += __shfl_down(s, off); q += __shfl_down(q, off); }
    __shared__ float ss[4], sq[4];
    if ((t & 63) == 0) { ss[t >> 6] = s; sq[t >> 6] = q; }
    __syncthreads();
    if (t == 0) {
        ps[row] = ss[0] + ss[1] + ss[2] + ss[3];
        pq[row] = sq[0] + sq[1] + sq[2] + sq[3];
    }
}

__global__ __launch_bounds__(256) void k_fin2(const float* __restrict__ ps,
        const float* __restrict__ pq, const float* __restrict__ g,
        const float* __restrict__ be, float* __restrict__ av, float* __restrict__ bv) {
    int o = threadIdx.x;
    float s = 0.f, q = 0.f;
    for (int b = 0; b < 16; ++b) { s += ps[b * 256 + o]; q += pq[b * 256 + o]; }
    float mean = s / 65536.0f;
    float var = q / 65536.0f - mean * mean;
    float a = g[o] * rsqrtf(var + BN_EPS);
    av[o] = a; bv[o] = be[o] - mean * a;
}

// ---------- final normalize+relu -> f32 out ----------
__global__ __launch_bounds__(256) void k_final(const unsigned short* __restrict__ h2,
        const float* __restrict__ av, const float* __restrict__ bv, float* __restrict__ out) {
    size_t i0 = ((size_t)blockIdx.x * 256 + threadIdx.x) * 8;
    int o = (int)((i0 >> 12) & 255);
    float a = av[o], b = bv[o];
    short8 v = *(const short8*)&h2[i0];
    f32x4 r0, r1;
    #pragma unroll
    for (int j = 0; j < 4; ++j) r0[j] = fmaxf(a * bf2f((unsigned short)v[j]) + b, 0.f);
    #pragma unroll
    for (int j = 0; j < 4; ++j) r1[j] = fmaxf(a * bf2f((unsigned short)v[4 + j]) + b, 0.f);
    *(f32x4*)&out[i0] = r0;
    *(f32x4*)&out[i0 + 4] = r1;
}

extern "C" void kernel_launch(void* const* d_in, const int* in_sizes, int n_in,
                              void* d_out, int out_size, void* d_ws, size_t ws_size,
                              hipStream_t stream) {
    const float* xyz1 = (const float*)d_in[0];
    const float* xyz2 = (const float*)d_in[1];
    const float* p1   = (const float*)d_in[2];
    const float* p2   = (const float*)d_in[3];
    const float* W1   = (const float*)d_in[4];
    const float* g1   = (const float*)d_in[5];
    const float* be1  = (const float*)d_in[6];
    const float* W2   = (const float*)d_in[7];
    const float* g2   = (const float*)d_in[8];
    const float* be2  = (const float*)d_in[9];
    float* out = (float*)d_out;
    char* ws = (char*)d_ws;

    unsigned short* Xt  = (unsigned short*)(ws);                    // 50,331,648 B
    unsigned short* h1  = (unsigned short*)(ws + 50331648);         // 33,554,432 B
    unsigned short* h2  = (unsigned short*)(ws + 83886080);         // 33,554,432 B
    // p2t shares h2's slot: p2t lifetime (k_tr_p2 -> k_build) ends before h2 is written (GEMM2)
    unsigned short* p2t = (unsigned short*)(ws + 83886080);         // 8,388,608 B
    unsigned short* W1b = (unsigned short*)(ws + 117440512);        // 196,608 B
    unsigned short* W2b = (unsigned short*)(ws + 117637120);        // 131,072 B
    int*   idx3 = (int*)(ws + 117768192);                           // 786,432 B
    float* w3   = (float*)(ws + 118554624);                         // 786,432 B
    float* ps1  = (float*)(ws + 119341056);                         // 262,144 B
    float* pq1  = (float*)(ws + 119603200);                         // 262,144 B
    float* ps2  = (float*)(ws + 119865344);                         // 16,384 B
    float* pq2  = (float*)(ws + 119881728);                         // 16,384 B
    float* a1v  = (float*)(ws + 119898112);
    float* b1v  = (float*)(ws + 119899136);
    float* a2v  = (float*)(ws + 119900160);
    float* b2v  = (float*)(ws + 119901184);

    k_convert<<<dim3(384), dim3(256), 0, stream>>>(W1, W2, W1b, W2b);
    k_knn<<<dim3(256), dim3(256), 0, stream>>>(xyz1, xyz2, idx3, w3);
    k_tr_p2<<<dim3(64, 16), dim3(256), 0, stream>>>(p2, p2t);
    k_build<<<dim3(64, 16), dim3(256), 0, stream>>>(p1, p2t, idx3, w3, Xt);
    // GEMM1: A = Xt (65536 x 384), B = W1b (256 x 384) -> h1[n][o]
    k_gemm<<<dim3(512, 2), dim3(256), 0, stream>>>(Xt, W1b, h1, 384, 256, 0);
    k_stats1<<<dim3(256), dim3(256), 0, stream>>>(h1, ps1, pq1);
    k_fin1<<<dim3(1), dim3(256), 0, stream>>>(ps1, pq1, g1, be1, a1v, b1v);
    k_norm1<<<dim3(8192), dim3(256), 0, stream>>>(h1, a1v, b1v);
    // GEMM2: A = W2b (256 x 256), B = h1 (65536 x 256) -> h2[b][o][n]
    k_gemm<<<dim3(2, 512), dim3(256), 0, stream>>>(W2b, h1, h2, 256, 4096, 1048576);
    k_stats2<<<dim3(4096), dim3(256), 0, stream>>>(h2, ps2, pq2);
    k_fin2<<<dim3(1), dim3(256), 0, stream>>>(ps2, pq2, g2, be2, a2v, b2v);
    k_final<<<dim3(8192), dim3(256), 0, stream>>>(h2, a2v, b2v, out);
}

// Round 4
// 201.061 us; speedup vs baseline: 2.3787x; 1.3806x over previous
//
#include <hip/hip_runtime.h>
#include <hip/hip_bf16.h>

typedef __attribute__((ext_vector_type(8))) short short8;
typedef __attribute__((ext_vector_type(4))) float f32x4;

#define BN_EPS 1e-5f

// ---------- bf16 helpers (RNE) ----------
__device__ __forceinline__ float bf2f(unsigned short u) {
    unsigned int x = ((unsigned int)u) << 16;
    union { unsigned int i; float f; } c; c.i = x; return c.f;
}
__device__ __forceinline__ unsigned short f2bf(float f) {
    union { float f; unsigned int i; } c; c.f = f;
    unsigned int lsb = (c.i >> 16) & 1u;
    c.i += 0x7fffu + lsb;
    return (unsigned short)(c.i >> 16);
}

// ---------- async global->LDS 16B ----------
typedef const unsigned int __attribute__((address_space(1)))* gas_t;
typedef unsigned int __attribute__((address_space(3)))* las_t;
__device__ __forceinline__ void gload_lds16(const void* src, void* ldsdst) {
    __builtin_amdgcn_global_load_lds((gas_t)src, (las_t)ldsdst, 16, 0, 0);
}

// ---------- convert weights to bf16 ----------
__global__ __launch_bounds__(256) void k_convert(const float* __restrict__ W1,
        const float* __restrict__ W2, unsigned short* __restrict__ W1b,
        unsigned short* __restrict__ W2b) {
    int i = blockIdx.x * 256 + threadIdx.x;
    if (i < 256 * 384) W1b[i] = f2bf(W1[i]);
    if (i < 256 * 256) W2b[i] = f2bf(W2[i]);
}

// ---------- 3-NN + weights: 4-way split, exact-f32 branchless top-3 ----------
__global__ __launch_bounds__(256) void k_knn(const float* __restrict__ xyz1,
        const float* __restrict__ xyz2, int* __restrict__ idx3, float* __restrict__ w3) {
    __shared__ f32x4 cand[1024];          // (x, y, z, |p|^2)
    __shared__ float mkd[64][13];         // 12 partial dists per query (+pad)
    __shared__ int   mki[64][13];         // 12 partial indices per query (+pad)
    int b = blockIdx.y;
    int n0 = blockIdx.x * 64;
    int t = threadIdx.x;
    const float* x2 = xyz2 + (size_t)b * 3072;
    for (int i = t; i < 1024; i += 256) {
        float x = x2[i], y = x2[1024 + i], z = x2[2048 + i];
        f32x4 v;
        v[0] = x; v[1] = y; v[2] = z; v[3] = x * x + y * y + z * z;
        cand[i] = v;
    }
    __syncthreads();
    int q = t & 63, s = t >> 6;
    int n = n0 + q;
    const float* x1 = xyz1 + (size_t)b * 12288;
    float px = x1[n], py = x1[4096 + n], pz = x1[8192 + n];
    float s1 = px * px + py * py + pz * pz;
    float d0 = 1e30f, d1 = 1e30f, d2 = 1e30f;
    int i0 = 0, i1 = 0, i2 = 0;
    int j0 = s * 256;
    #pragma unroll 4
    for (int jj = 0; jj < 256; ++jj) {
        int j = j0 + jj;
        f32x4 v = cand[j];
        // exact same expression tree as the passing serial version:
        float dot = px * v[0] + py * v[1] + pz * v[2];
        float d = -2.0f * dot; d += s1; d += v[3];
        bool b0 = d < d0, b1 = d < d1, b2 = d < d2;
        d2 = b1 ? d1 : (b2 ? d : d2);
        i2 = b1 ? i1 : (b2 ? j : i2);
        d1 = b0 ? d0 : (b1 ? d : d1);
        i1 = b0 ? i0 : (b1 ? j : i1);
        d0 = b0 ? d : d0;
        i0 = b0 ? j : i0;
    }
    mkd[q][s * 3 + 0] = d0; mki[q][s * 3 + 0] = i0;
    mkd[q][s * 3 + 1] = d1; mki[q][s * 3 + 1] = i1;
    mkd[q][s * 3 + 2] = d2; mki[q][s * 3 + 2] = i2;
    __syncthreads();
    if (t < 64) {
        // merge 12 sorted-by-(d,idx) partials in ascending split (=index) order;
        // strict < keeps the earlier (lower-index) entry on ties, matching top_k.
        float e0 = 1e30f, e1 = 1e30f, e2 = 1e30f;
        int a0 = 0, a1 = 0, a2 = 0;
        #pragma unroll
        for (int m = 0; m < 12; ++m) {
            float d = mkd[t][m]; int j = mki[t][m];
            bool b0 = d < e0, b1 = d < e1, b2 = d < e2;
            e2 = b1 ? e1 : (b2 ? d : e2);
            a2 = b1 ? a1 : (b2 ? j : a2);
            e1 = b0 ? e0 : (b1 ? d : e1);
            a1 = b0 ? a0 : (b1 ? j : a1);
            e0 = b0 ? d : e0;
            a0 = b0 ? j : a0;
        }
        float dd0 = fmaxf(e0, 1e-10f), dd1 = fmaxf(e1, 1e-10f), dd2 = fmaxf(e2, 1e-10f);
        float w0 = 1.f / dd0, w1 = 1.f / dd1, w2 = 1.f / dd2;
        float sw = w0 + w1 + w2; w0 /= sw; w1 /= sw; w2 /= sw;
        size_t base = ((size_t)b * 4096 + n0 + t) * 3;
        idx3[base] = a0; idx3[base + 1] = a1; idx3[base + 2] = a2;
        w3[base] = w0; w3[base + 1] = w1; w3[base + 2] = w2;
    }
}

// ---------- transpose p2 [b][256][1024] f32 -> p2t [b][1024][256] bf16 ----------
__global__ __launch_bounds__(256) void k_tr_p2(const float* __restrict__ p2,
        unsigned short* __restrict__ p2t) {
    __shared__ float tile[64][65];
    int b = blockIdx.y;
    int n0 = (blockIdx.x & 15) * 64;
    int c0 = (blockIdx.x >> 4) * 64;
    int t = threadIdx.x;
    const float* src = p2 + (size_t)b * 256 * 1024 + (size_t)c0 * 1024 + n0;
    #pragma unroll
    for (int i = 0; i < 16; ++i) {
        int e = i * 256 + t;
        int c = e >> 6, n = e & 63;
        tile[c][n] = src[(size_t)c * 1024 + n];
    }
    __syncthreads();
    int n = t >> 2, cs = (t & 3) * 16;
    unsigned short* dst = p2t + ((size_t)b * 1024 + n0 + n) * 256 + c0 + cs;
    short8 o0, o1;
    #pragma unroll
    for (int i = 0; i < 8; ++i) o0[i] = (short)f2bf(tile[cs + i][n]);
    #pragma unroll
    for (int i = 0; i < 8; ++i) o1[i] = (short)f2bf(tile[cs + 8 + i][n]);
    *(short8*)dst = o0;
    *(short8*)(dst + 8) = o1;
}

// ---------- build Xt[b*4096+n][384] = concat(points1^T, interp) in bf16 ----------
__global__ __launch_bounds__(256) void k_build(const float* __restrict__ p1,
        const unsigned short* __restrict__ p2t, const int* __restrict__ idx3,
        const float* __restrict__ w3, unsigned short* __restrict__ Xt) {
    __shared__ float tile[64][65];
    __shared__ int sidx[64][3];
    __shared__ float sw[64][3];
    int b = blockIdx.y;
    int n0 = blockIdx.x * 64;
    int t = threadIdx.x;
    if (t < 192) {
        size_t base = ((size_t)b * 4096 + n0) * 3;
        ((int*)sidx)[t] = idx3[base + t];
        ((float*)sw)[t] = w3[base + t];
    }
    const float* p1b = p1 + (size_t)b * 128 * 4096 + n0;
    unsigned short* Xb = Xt + ((size_t)b * 4096 + n0) * 384;
    // part A: transpose p1 (c = 0..127)
    for (int c0 = 0; c0 < 128; c0 += 64) {
        __syncthreads();
        #pragma unroll
        for (int i = 0; i < 16; ++i) {
            int e = i * 256 + t;
            int c = e >> 6, nn = e & 63;
            tile[c][nn] = p1b[(size_t)(c0 + c) * 4096 + nn];
        }
        __syncthreads();
        int nn = t >> 2, cs = (t & 3) * 16;
        unsigned short* dst = Xb + (size_t)nn * 384 + c0 + cs;
        short8 o0, o1;
        #pragma unroll
        for (int i = 0; i < 8; ++i) o0[i] = (short)f2bf(tile[cs + i][nn]);
        #pragma unroll
        for (int i = 0; i < 8; ++i) o1[i] = (short)f2bf(tile[cs + 8 + i][nn]);
        *(short8*)dst = o0;
        *(short8*)(dst + 8) = o1;
    }
    // part B: interpolation (c = 128..383), 4 lanes per point, 64 ch each
    {
        int nn = t >> 2, cs = (t & 3) * 64;
        const unsigned short* pb = p2t + (size_t)b * 1024 * 256 + cs;
        const unsigned short* r0 = pb + (size_t)sidx[nn][0] * 256;
        const unsigned short* r1 = pb + (size_t)sidx[nn][1] * 256;
        const unsigned short* r2 = pb + (size_t)sidx[nn][2] * 256;
        float w0 = sw[nn][0], w1 = sw[nn][1], w2 = sw[nn][2];
        unsigned short* dst = Xb + (size_t)nn * 384 + 128 + cs;
        #pragma unroll
        for (int j = 0; j < 8; ++j) {
            short8 a = *(const short8*)(r0 + j * 8);
            short8 bb = *(const short8*)(r1 + j * 8);
            short8 cc = *(const short8*)(r2 + j * 8);
            short8 o;
            #pragma unroll
            for (int e = 0; e < 8; ++e) {
                float v = w0 * bf2f((unsigned short)a[e]) + w1 * bf2f((unsigned short)bb[e])
                        + w2 * bf2f((unsigned short)cc[e]);
                o[e] = (short)f2bf(v);
            }
            *(short8*)(dst + j * 8) = o;
        }
    }
}

// ---------- GEMM: C[ar][bc] = sum_k A[ar][k]*B[bc][k], A,B row-major [rows][Kdim] bf16 ----------
// out index = arow*sA + (brow>>12)*sBatch + (brow&4095)
__global__ __launch_bounds__(256) void k_gemm(const unsigned short* __restrict__ A,
        const unsigned short* __restrict__ B, unsigned short* __restrict__ C,
        int Kdim, size_t sA, size_t sBatch) {
    __shared__ unsigned short lA[128 * 32];
    __shared__ unsigned short lB[128 * 32];
    int t = threadIdx.x;
    int w = t >> 6, lane = t & 63;
    int ar0 = blockIdx.x * 128, br0 = blockIdx.y * 128;
    int war = (w >> 1) * 64, wbr = (w & 1) * 64;
    f32x4 acc[4][4] = {};
    int rlo = lane & 15, khi = lane >> 4;
    for (int kk = 0; kk < Kdim; kk += 32) {
        #pragma unroll
        for (int it = 0; it < 2; ++it) {
            int q = it * 256 + w * 64 + lane;
            int row = q >> 2, kc = q & 3;
            const unsigned short* srcA = A + (size_t)(ar0 + row) * Kdim + kk + ((kc ^ (row & 3)) << 3);
            gload_lds16(srcA, &lA[(size_t)(it * 256 + w * 64) * 8]);
            const unsigned short* srcB = B + (size_t)(br0 + row) * Kdim + kk + ((kc ^ (row & 3)) << 3);
            gload_lds16(srcB, &lB[(size_t)(it * 256 + w * 64) * 8]);
        }
        __syncthreads();
        short8 af[4], bfr[4];
        #pragma unroll
        for (int mi = 0; mi < 4; ++mi) {
            int r = war + mi * 16 + rlo;
            af[mi] = *(const short8*)&lA[(size_t)(r * 4 + (khi ^ (r & 3))) * 8];
        }
        #pragma unroll
        for (int ni = 0; ni < 4; ++ni) {
            int r = wbr + ni * 16 + rlo;
            bfr[ni] = *(const short8*)&lB[(size_t)(r * 4 + (khi ^ (r & 3))) * 8];
        }
        #pragma unroll
        for (int mi = 0; mi < 4; ++mi)
            #pragma unroll
            for (int ni = 0; ni < 4; ++ni)
                acc[mi][ni] = __builtin_amdgcn_mfma_f32_16x16x32_bf16(af[mi], bfr[ni], acc[mi][ni], 0, 0, 0);
        __syncthreads();
    }
    #pragma unroll
    for (int mi = 0; mi < 4; ++mi) {
        #pragma unroll
        for (int ni = 0; ni < 4; ++ni) {
            #pragma unroll
            for (int r = 0; r < 4; ++r) {
                int arow = ar0 + war + mi * 16 + khi * 4 + r;
                int brow = br0 + wbr + ni * 16 + rlo;
                size_t oidx = (size_t)arow * sA + (size_t)(brow >> 12) * sBatch + (size_t)(brow & 4095);
                C[oidx] = f2bf(acc[mi][ni][r]);
            }
        }
    }
}

// ---------- BN stats stage 1 over h1 [65536][256] ----------
__global__ __launch_bounds__(256) void k_stats1(const unsigned short* __restrict__ h1,
        float* __restrict__ ps, float* __restrict__ pq) {
    int c = threadIdx.x;
    size_t r0 = (size_t)blockIdx.x * 256;
    float s = 0.f, q = 0.f;
    for (int i = 0; i < 256; ++i) {
        float v = bf2f(h1[(r0 + i) * 256 + c]);
        s += v; q += v * v;
    }
    ps[blockIdx.x * 256 + c] = s;
    pq[blockIdx.x * 256 + c] = q;
}

__global__ __launch_bounds__(256) void k_fin1(const float* __restrict__ ps,
        const float* __restrict__ pq, const float* __restrict__ g,
        const float* __restrict__ be, float* __restrict__ av, float* __restrict__ bv) {
    int c = threadIdx.x;
    float s = 0.f, q = 0.f;
    for (int i = 0; i < 256; ++i) { s += ps[i * 256 + c]; q += pq[i * 256 + c]; }
    float mean = s / 65536.0f;
    float var = q / 65536.0f - mean * mean;
    float a = g[c] * rsqrtf(var + BN_EPS);
    av[c] = a; bv[c] = be[c] - mean * a;
}

// ---------- normalize+relu h1 in place ----------
__global__ __launch_bounds__(256) void k_norm1(unsigned short* __restrict__ h1,
        const float* __restrict__ av, const float* __restrict__ bv) {
    size_t i0 = ((size_t)blockIdx.x * 256 + threadIdx.x) * 8;
    int c0 = (int)(i0 & 255);
    short8 v = *(short8*)&h1[i0];
    short8 o;
    #pragma unroll
    for (int j = 0; j < 8; ++j) {
        float x = bf2f((unsigned short)v[j]);
        float y = av[c0 + j] * x + bv[c0 + j];
        o[j] = (short)f2bf(fmaxf(y, 0.f));
    }
    *(short8*)&h1[i0] = o;
}

// ---------- BN stats over h2 [16][256][4096]: one block per (b,o) row ----------
__global__ __launch_bounds__(256) void k_stats2(const unsigned short* __restrict__ h2,
        float* __restrict__ ps, float* __restrict__ pq) {
    size_t row = blockIdx.x;
    const unsigned short* p = h2 + row * 4096;
    int t = threadIdx.x;
    float s = 0.f, q = 0.f;
    #pragma unroll
    for (int j = 0; j < 2; ++j) {
        short8 v = *(const short8*)&p[t * 16 + j * 8];
        #pragma unroll
        for (int e = 0; e < 8; ++e) {
            float x = bf2f((unsigned short)v[e]);
            s += x; q += x * x;
        }
    }
    #pragma unroll
    for (int off = 32; off; off >>= 1) { s += __shfl_down(s, off); q += __shfl_down(q, off); }
    __shared__ float ss[4], sq[4];
    if ((t & 63) == 0) { ss[t >> 6] = s; sq[t >> 6] = q; }
    __syncthreads();
    if (t == 0) {
        ps[row] = ss[0] + ss[1] + ss[2] + ss[3];
        pq[row] = sq[0] + sq[1] + sq[2] + sq[3];
    }
}

__global__ __launch_bounds__(256) void k_fin2(const float* __restrict__ ps,
        const float* __restrict__ pq, const float* __restrict__ g,
        const float* __restrict__ be, float* __restrict__ av, float* __restrict__ bv) {
    int o = threadIdx.x;
    float s = 0.f, q = 0.f;
    for (int b = 0; b < 16; ++b) { s += ps[b * 256 + o]; q += pq[b * 256 + o]; }
    float mean = s / 65536.0f;
    float var = q / 65536.0f - mean * mean;
    float a = g[o] * rsqrtf(var + BN_EPS);
    av[o] = a; bv[o] = be[o] - mean * a;
}

// ---------- final normalize+relu -> f32 out ----------
__global__ __launch_bounds__(256) void k_final(const unsigned short* __restrict__ h2,
        const float* __restrict__ av, const float* __restrict__ bv, float* __restrict__ out) {
    size_t i0 = ((size_t)blockIdx.x * 256 + threadIdx.x) * 8;
    int o = (int)((i0 >> 12) & 255);
    float a = av[o], b = bv[o];
    short8 v = *(const short8*)&h2[i0];
    f32x4 r0, r1;
    #pragma unroll
    for (int j = 0; j < 4; ++j) r0[j] = fmaxf(a * bf2f((unsigned short)v[j]) + b, 0.f);
    #pragma unroll
    for (int j = 0; j < 4; ++j) r1[j] = fmaxf(a * bf2f((unsigned short)v[4 + j]) + b, 0.f);
    *(f32x4*)&out[i0] = r0;
    *(f32x4*)&out[i0 + 4] = r1;
}

extern "C" void kernel_launch(void* const* d_in, const int* in_sizes, int n_in,
                              void* d_out, int out_size, void* d_ws, size_t ws_size,
                              hipStream_t stream) {
    const float* xyz1 = (const float*)d_in[0];
    const float* xyz2 = (const float*)d_in[1];
    const float* p1   = (const float*)d_in[2];
    const float* p2   = (const float*)d_in[3];
    const float* W1   = (const float*)d_in[4];
    const float* g1   = (const float*)d_in[5];
    const float* be1  = (const float*)d_in[6];
    const float* W2   = (const float*)d_in[7];
    const float* g2   = (const float*)d_in[8];
    const float* be2  = (const float*)d_in[9];
    float* out = (float*)d_out;
    char* ws = (char*)d_ws;

    unsigned short* Xt  = (unsigned short*)(ws);                    // 50,331,648 B
    unsigned short* h1  = (unsigned short*)(ws + 50331648);         // 33,554,432 B
    unsigned short* h2  = (unsigned short*)(ws + 83886080);         // 33,554,432 B
    // p2t shares h2's slot: p2t lifetime (k_tr_p2 -> k_build) ends before h2 is written (GEMM2)
    unsigned short* p2t = (unsigned short*)(ws + 83886080);         // 8,388,608 B
    unsigned short* W1b = (unsigned short*)(ws + 117440512);        // 196,608 B
    unsigned short* W2b = (unsigned short*)(ws + 117637120);        // 131,072 B
    int*   idx3 = (int*)(ws + 117768192);                           // 786,432 B
    float* w3   = (float*)(ws + 118554624);                         // 786,432 B
    float* ps1  = (float*)(ws + 119341056);                         // 262,144 B
    float* pq1  = (float*)(ws + 119603200);                         // 262,144 B
    float* ps2  = (float*)(ws + 119865344);                         // 16,384 B
    float* pq2  = (float*)(ws + 119881728);                         // 16,384 B
    float* a1v  = (float*)(ws + 119898112);
    float* b1v  = (float*)(ws + 119899136);
    float* a2v  = (float*)(ws + 119900160);
    float* b2v  = (float*)(ws + 119901184);

    k_convert<<<dim3(384), dim3(256), 0, stream>>>(W1, W2, W1b, W2b);
    k_knn<<<dim3(64, 16), dim3(256), 0, stream>>>(xyz1, xyz2, idx3, w3);
    k_tr_p2<<<dim3(64, 16), dim3(256), 0, stream>>>(p2, p2t);
    k_build<<<dim3(64, 16), dim3(256), 0, stream>>>(p1, p2t, idx3, w3, Xt);
    // GEMM1: A = Xt (65536 x 384), B = W1b (256 x 384) -> h1[n][o]
    k_gemm<<<dim3(512, 2), dim3(256), 0, stream>>>(Xt, W1b, h1, 384, 256, 0);
    k_stats1<<<dim3(256), dim3(256), 0, stream>>>(h1, ps1, pq1);
    k_fin1<<<dim3(1), dim3(256), 0, stream>>>(ps1, pq1, g1, be1, a1v, b1v);
    k_norm1<<<dim3(8192), dim3(256), 0, stream>>>(h1, a1v, b1v);
    // GEMM2: A = W2b (256 x 256), B = h1 (65536 x 256) -> h2[b][o][n]
    k_gemm<<<dim3(2, 512), dim3(256), 0, stream>>>(W2b, h1, h2, 256, 4096, 1048576);
    k_stats2<<<dim3(4096), dim3(256), 0, stream>>>(h2, ps2, pq2);
    k_fin2<<<dim3(1), dim3(256), 0, stream>>>(ps2, pq2, g2, be2, a2v, b2v);
    k_final<<<dim3(8192), dim3(256), 0, stream>>>(h2, a2v, b2v, out);
}

// Round 5
// 185.748 us; speedup vs baseline: 2.5748x; 1.0824x over previous
//
#include <hip/hip_runtime.h>
#include <hip/hip_bf16.h>

typedef __attribute__((ext_vector_type(8))) short short8;
typedef __attribute__((ext_vector_type(4))) float f32x4;

#define BN_EPS 1e-5f

// ---------- bf16 helpers (RNE) ----------
__device__ __forceinline__ float bf2f(unsigned short u) {
    unsigned int x = ((unsigned int)u) << 16;
    union { unsigned int i; float f; } c; c.i = x; return c.f;
}
__device__ __forceinline__ unsigned short f2bf(float f) {
    union { float f; unsigned int i; } c; c.f = f;
    unsigned int lsb = (c.i >> 16) & 1u;
    c.i += 0x7fffu + lsb;
    return (unsigned short)(c.i >> 16);
}
__device__ __forceinline__ unsigned long long pack4bf(float a, float b, float c, float d) {
    unsigned long long r = (unsigned long long)f2bf(a)
        | ((unsigned long long)f2bf(b) << 16)
        | ((unsigned long long)f2bf(c) << 32)
        | ((unsigned long long)f2bf(d) << 48);
    return r;
}

// ---------- async global->LDS 16B ----------
typedef const unsigned int __attribute__((address_space(1)))* gas_t;
typedef unsigned int __attribute__((address_space(3)))* las_t;
__device__ __forceinline__ void gload_lds16(const void* src, void* ldsdst) {
    __builtin_amdgcn_global_load_lds((gas_t)src, (las_t)ldsdst, 16, 0, 0);
}

// ---------- convert weights to bf16 ----------
__global__ __launch_bounds__(256) void k_convert(const float* __restrict__ W1,
        const float* __restrict__ W2, unsigned short* __restrict__ W1b,
        unsigned short* __restrict__ W2b) {
    int i = blockIdx.x * 256 + threadIdx.x;
    if (i < 256 * 384) W1b[i] = f2bf(W1[i]);
    if (i < 256 * 256) W2b[i] = f2bf(W2[i]);
}

// ---------- 3-NN + weights: 4-way split, exact-f32 branchless top-3 ----------
__global__ __launch_bounds__(256) void k_knn(const float* __restrict__ xyz1,
        const float* __restrict__ xyz2, int* __restrict__ idx3, float* __restrict__ w3) {
    __shared__ f32x4 cand[1024];          // (x, y, z, |p|^2)
    __shared__ float mkd[64][13];         // 12 partial dists per query (+pad)
    __shared__ int   mki[64][13];         // 12 partial indices per query (+pad)
    int b = blockIdx.y;
    int n0 = blockIdx.x * 64;
    int t = threadIdx.x;
    const float* x2 = xyz2 + (size_t)b * 3072;
    for (int i = t; i < 1024; i += 256) {
        float x = x2[i], y = x2[1024 + i], z = x2[2048 + i];
        f32x4 v;
        v[0] = x; v[1] = y; v[2] = z; v[3] = x * x + y * y + z * z;
        cand[i] = v;
    }
    __syncthreads();
    int q = t & 63, s = t >> 6;
    int n = n0 + q;
    const float* x1 = xyz1 + (size_t)b * 12288;
    float px = x1[n], py = x1[4096 + n], pz = x1[8192 + n];
    float s1 = px * px + py * py + pz * pz;
    float d0 = 1e30f, d1 = 1e30f, d2 = 1e30f;
    int i0 = 0, i1 = 0, i2 = 0;
    int j0 = s * 256;
    #pragma unroll 4
    for (int jj = 0; jj < 256; ++jj) {
        int j = j0 + jj;
        f32x4 v = cand[j];
        // exact same expression tree as the passing serial version:
        float dot = px * v[0] + py * v[1] + pz * v[2];
        float d = -2.0f * dot; d += s1; d += v[3];
        bool b0 = d < d0, b1 = d < d1, b2 = d < d2;
        d2 = b1 ? d1 : (b2 ? d : d2);
        i2 = b1 ? i1 : (b2 ? j : i2);
        d1 = b0 ? d0 : (b1 ? d : d1);
        i1 = b0 ? i0 : (b1 ? j : i1);
        d0 = b0 ? d : d0;
        i0 = b0 ? j : i0;
    }
    mkd[q][s * 3 + 0] = d0; mki[q][s * 3 + 0] = i0;
    mkd[q][s * 3 + 1] = d1; mki[q][s * 3 + 1] = i1;
    mkd[q][s * 3 + 2] = d2; mki[q][s * 3 + 2] = i2;
    __syncthreads();
    if (t < 64) {
        // merge 12 partials in ascending split (=index) order;
        // strict < keeps the earlier (lower-index) entry on ties, matching top_k.
        float e0 = 1e30f, e1 = 1e30f, e2 = 1e30f;
        int a0 = 0, a1 = 0, a2 = 0;
        #pragma unroll
        for (int m = 0; m < 12; ++m) {
            float d = mkd[t][m]; int j = mki[t][m];
            bool b0 = d < e0, b1 = d < e1, b2 = d < e2;
            e2 = b1 ? e1 : (b2 ? d : e2);
            a2 = b1 ? a1 : (b2 ? j : a2);
            e1 = b0 ? e0 : (b1 ? d : e1);
            a1 = b0 ? a0 : (b1 ? j : a1);
            e0 = b0 ? d : e0;
            a0 = b0 ? j : a0;
        }
        float dd0 = fmaxf(e0, 1e-10f), dd1 = fmaxf(e1, 1e-10f), dd2 = fmaxf(e2, 1e-10f);
        float w0 = 1.f / dd0, w1 = 1.f / dd1, w2 = 1.f / dd2;
        float sw = w0 + w1 + w2; w0 /= sw; w1 /= sw; w2 /= sw;
        size_t base = ((size_t)b * 4096 + n0 + t) * 3;
        idx3[base] = a0; idx3[base + 1] = a1; idx3[base + 2] = a2;
        w3[base] = w0; w3[base + 1] = w1; w3[base + 2] = w2;
    }
}

// ---------- transpose p2 [b][256][1024] f32 -> p2t [b][1024][256] bf16 ----------
// 4x4 register-block transpose; per block: 128 c x 32 n.
__global__ __launch_bounds__(256) void k_tr_p2(const float* __restrict__ p2,
        unsigned short* __restrict__ p2t) {
    __shared__ unsigned short btile[32][136];
    int b = blockIdx.y;
    int n0 = (blockIdx.x & 31) * 32;
    int c0 = (blockIdx.x >> 5) * 128;
    int t = threadIdx.x;
    const float* src = p2 + (size_t)b * 256 * 1024 + (size_t)c0 * 1024 + n0;
    int c4 = (t >> 3) * 4, n4 = (t & 7) * 4;
    f32x4 q0 = *(const f32x4*)&src[(size_t)(c4 + 0) * 1024 + n4];
    f32x4 q1 = *(const f32x4*)&src[(size_t)(c4 + 1) * 1024 + n4];
    f32x4 q2 = *(const f32x4*)&src[(size_t)(c4 + 2) * 1024 + n4];
    f32x4 q3 = *(const f32x4*)&src[(size_t)(c4 + 3) * 1024 + n4];
    #pragma unroll
    for (int j = 0; j < 4; ++j) {
        *(unsigned long long*)&btile[n4 + j][c4] = pack4bf(q0[j], q1[j], q2[j], q3[j]);
    }
    __syncthreads();
    int nn = t >> 3, cs = (t & 7) * 16;
    short8 v0 = *(const short8*)&btile[nn][cs];
    short8 v1 = *(const short8*)&btile[nn][cs + 8];
    unsigned short* dst = p2t + ((size_t)b * 1024 + n0 + nn) * 256 + c0 + cs;
    *(short8*)dst = v0;
    *(short8*)(dst + 8) = v1;
}

// ---------- build Xt[b*4096+n][384] = concat(points1^T, interp) in bf16 ----------
// per block: 32 n-points, full 384 channels; 4x4 register-block transpose for p1.
__global__ __launch_bounds__(256) void k_build(const float* __restrict__ p1,
        const unsigned short* __restrict__ p2t, const int* __restrict__ idx3,
        const float* __restrict__ w3, unsigned short* __restrict__ Xt) {
    __shared__ unsigned short btile[32][136];
    __shared__ int sidx[32][3];
    __shared__ float sw[32][3];
    int b = blockIdx.y;
    int n0 = blockIdx.x * 32;
    int t = threadIdx.x;
    if (t < 96) {
        size_t base = ((size_t)b * 4096 + n0) * 3;
        ((int*)sidx)[t] = idx3[base + t];
        ((float*)sw)[t] = w3[base + t];
    }
    const float* p1b = p1 + (size_t)b * 128 * 4096 + n0;
    unsigned short* Xb = Xt + ((size_t)b * 4096 + n0) * 384;
    // phase 1: load p1 [128 c][32 n] as 4x4 f32 blocks, transpose in regs -> LDS [n][c]
    int c4 = (t >> 3) * 4, n4 = (t & 7) * 4;
    f32x4 q0 = *(const f32x4*)&p1b[(size_t)(c4 + 0) * 4096 + n4];
    f32x4 q1 = *(const f32x4*)&p1b[(size_t)(c4 + 1) * 4096 + n4];
    f32x4 q2 = *(const f32x4*)&p1b[(size_t)(c4 + 2) * 4096 + n4];
    f32x4 q3 = *(const f32x4*)&p1b[(size_t)(c4 + 3) * 4096 + n4];
    #pragma unroll
    for (int j = 0; j < 4; ++j) {
        *(unsigned long long*)&btile[n4 + j][c4] = pack4bf(q0[j], q1[j], q2[j], q3[j]);
    }
    __syncthreads();
    // phase 2: copy LDS rows -> Xt cols [0,128)
    {
        int nn = t >> 3, cs = (t & 7) * 16;
        short8 v0 = *(const short8*)&btile[nn][cs];
        short8 v1 = *(const short8*)&btile[nn][cs + 8];
        unsigned short* dst = Xb + (size_t)nn * 384 + cs;
        *(short8*)dst = v0;
        *(short8*)(dst + 8) = v1;
    }
    // part B: interpolation -> Xt cols [128,384); 8 lanes x 32 ch per point
    {
        int nn = t >> 3, cs = (t & 7) * 32;
        const unsigned short* pb = p2t + (size_t)b * 1024 * 256 + cs;
        const unsigned short* r0 = pb + (size_t)sidx[nn][0] * 256;
        const unsigned short* r1 = pb + (size_t)sidx[nn][1] * 256;
        const unsigned short* r2 = pb + (size_t)sidx[nn][2] * 256;
        float w0 = sw[nn][0], w1 = sw[nn][1], w2 = sw[nn][2];
        unsigned short* dst = Xb + (size_t)nn * 384 + 128 + cs;
        #pragma unroll
        for (int j = 0; j < 4; ++j) {
            short8 a = *(const short8*)(r0 + j * 8);
            short8 bb = *(const short8*)(r1 + j * 8);
            short8 cc = *(const short8*)(r2 + j * 8);
            short8 o;
            #pragma unroll
            for (int e = 0; e < 8; ++e) {
                float v = w0 * bf2f((unsigned short)a[e]) + w1 * bf2f((unsigned short)bb[e])
                        + w2 * bf2f((unsigned short)cc[e]);
                o[e] = (short)f2bf(v);
            }
            *(short8*)(dst + j * 8) = o;
        }
    }
}

// ---------- GEMM: C[ar][bc] = sum_k A[ar][k]*B[bc][k], A,B row-major [rows][Kdim] bf16 ----------
// out index = arow*sA + (brow>>12)*sBatch + (brow&4095)
__global__ __launch_bounds__(256) void k_gemm(const unsigned short* __restrict__ A,
        const unsigned short* __restrict__ B, unsigned short* __restrict__ C,
        int Kdim, size_t sA, size_t sBatch) {
    __shared__ unsigned short lA[128 * 32];
    __shared__ unsigned short lB[128 * 32];
    int t = threadIdx.x;
    int w = t >> 6, lane = t & 63;
    int ar0 = blockIdx.x * 128, br0 = blockIdx.y * 128;
    int war = (w >> 1) * 64, wbr = (w & 1) * 64;
    f32x4 acc[4][4] = {};
    int rlo = lane & 15, khi = lane >> 4;
    for (int kk = 0; kk < Kdim; kk += 32) {
        #pragma unroll
        for (int it = 0; it < 2; ++it) {
            int q = it * 256 + w * 64 + lane;
            int row = q >> 2, kc = q & 3;
            const unsigned short* srcA = A + (size_t)(ar0 + row) * Kdim + kk + ((kc ^ (row & 3)) << 3);
            gload_lds16(srcA, &lA[(size_t)(it * 256 + w * 64) * 8]);
            const unsigned short* srcB = B + (size_t)(br0 + row) * Kdim + kk + ((kc ^ (row & 3)) << 3);
            gload_lds16(srcB, &lB[(size_t)(it * 256 + w * 64) * 8]);
        }
        __syncthreads();
        short8 af[4], bfr[4];
        #pragma unroll
        for (int mi = 0; mi < 4; ++mi) {
            int r = war + mi * 16 + rlo;
            af[mi] = *(const short8*)&lA[(size_t)(r * 4 + (khi ^ (r & 3))) * 8];
        }
        #pragma unroll
        for (int ni = 0; ni < 4; ++ni) {
            int r = wbr + ni * 16 + rlo;
            bfr[ni] = *(const short8*)&lB[(size_t)(r * 4 + (khi ^ (r & 3))) * 8];
        }
        #pragma unroll
        for (int mi = 0; mi < 4; ++mi)
            #pragma unroll
            for (int ni = 0; ni < 4; ++ni)
                acc[mi][ni] = __builtin_amdgcn_mfma_f32_16x16x32_bf16(af[mi], bfr[ni], acc[mi][ni], 0, 0, 0);
        __syncthreads();
    }
    #pragma unroll
    for (int mi = 0; mi < 4; ++mi) {
        #pragma unroll
        for (int ni = 0; ni < 4; ++ni) {
            #pragma unroll
            for (int r = 0; r < 4; ++r) {
                int arow = ar0 + war + mi * 16 + khi * 4 + r;
                int brow = br0 + wbr + ni * 16 + rlo;
                size_t oidx = (size_t)arow * sA + (size_t)(brow >> 12) * sBatch + (size_t)(brow & 4095);
                C[oidx] = f2bf(acc[mi][ni][r]);
            }
        }
    }
}

// ---------- BN stats stage 1 over h1 [65536][256] ----------
__global__ __launch_bounds__(256) void k_stats1(const unsigned short* __restrict__ h1,
        float* __restrict__ ps, float* __restrict__ pq) {
    int c = threadIdx.x;
    size_t r0 = (size_t)blockIdx.x * 256;
    float s = 0.f, q = 0.f;
    for (int i = 0; i < 256; ++i) {
        float v = bf2f(h1[(r0 + i) * 256 + c]);
        s += v; q += v * v;
    }
    ps[blockIdx.x * 256 + c] = s;
    pq[blockIdx.x * 256 + c] = q;
}

__global__ __launch_bounds__(256) void k_fin1(const float* __restrict__ ps,
        const float* __restrict__ pq, const float* __restrict__ g,
        const float* __restrict__ be, float* __restrict__ av, float* __restrict__ bv) {
    int c = threadIdx.x;
    float s = 0.f, q = 0.f;
    for (int i = 0; i < 256; ++i) { s += ps[i * 256 + c]; q += pq[i * 256 + c]; }
    float mean = s / 65536.0f;
    float var = q / 65536.0f - mean * mean;
    float a = g[c] * rsqrtf(var + BN_EPS);
    av[c] = a; bv[c] = be[c] - mean * a;
}

// ---------- normalize+relu h1 in place ----------
__global__ __launch_bounds__(256) void k_norm1(unsigned short* __restrict__ h1,
        const float* __restrict__ av, const float* __restrict__ bv) {
    size_t i0 = ((size_t)blockIdx.x * 256 + threadIdx.x) * 8;
    int c0 = (int)(i0 & 255);
    short8 v = *(short8*)&h1[i0];
    short8 o;
    #pragma unroll
    for (int j = 0; j < 8; ++j) {
        float x = bf2f((unsigned short)v[j]);
        float y = av[c0 + j] * x + bv[c0 + j];
        o[j] = (short)f2bf(fmaxf(y, 0.f));
    }
    *(short8*)&h1[i0] = o;
}

// ---------- BN stats over h2 [16][256][4096]: one block per (b,o) row ----------
__global__ __launch_bounds__(256) void k_stats2(const unsigned short* __restrict__ h2,
        float* __restrict__ ps, float* __restrict__ pq) {
    size_t row = blockIdx.x;
    const unsigned short* p = h2 + row * 4096;
    int t = threadIdx.x;
    float s = 0.f, q = 0.f;
    #pragma unroll
    for (int j = 0; j < 2; ++j) {
        short8 v = *(const short8*)&p[t * 16 + j * 8];
        #pragma unroll
        for (int e = 0; e < 8; ++e) {
            float x = bf2f((unsigned short)v[e]);
            s += x; q += x * x;
        }
    }
    #pragma unroll
    for (int off = 32; off; off >>= 1) { s += __shfl_down(s, off); q += __shfl_down(q, off); }
    __shared__ float ss[4], sq[4];
    if ((t & 63) == 0) { ss[t >> 6] = s; sq[t >> 6] = q; }
    __syncthreads();
    if (t == 0) {
        ps[row] = ss[0] + ss[1] + ss[2] + ss[3];
        pq[row] = sq[0] + sq[1] + sq[2] + sq[3];
    }
}

__global__ __launch_bounds__(256) void k_fin2(const float* __restrict__ ps,
        const float* __restrict__ pq, const float* __restrict__ g,
        const float* __restrict__ be, float* __restrict__ av, float* __restrict__ bv) {
    int o = threadIdx.x;
    float s = 0.f, q = 0.f;
    for (int b = 0; b < 16; ++b) { s += ps[b * 256 + o]; q += pq[b * 256 + o]; }
    float mean = s / 65536.0f;
    float var = q / 65536.0f - mean * mean;
    float a = g[o] * rsqrtf(var + BN_EPS);
    av[o] = a; bv[o] = be[o] - mean * a;
}

// ---------- final normalize+relu -> f32 out ----------
__global__ __launch_bounds__(256) void k_final(const unsigned short* __restrict__ h2,
        const float* __restrict__ av, const float* __restrict__ bv, float* __restrict__ out) {
    size_t i0 = ((size_t)blockIdx.x * 256 + threadIdx.x) * 8;
    int o = (int)((i0 >> 12) & 255);
    float a = av[o], b = bv[o];
    short8 v = *(const short8*)&h2[i0];
    f32x4 r0, r1;
    #pragma unroll
    for (int j = 0; j < 4; ++j) r0[j] = fmaxf(a * bf2f((unsigned short)v[j]) + b, 0.f);
    #pragma unroll
    for (int j = 0; j < 4; ++j) r1[j] = fmaxf(a * bf2f((unsigned short)v[4 + j]) + b, 0.f);
    *(f32x4*)&out[i0] = r0;
    *(f32x4*)&out[i0 + 4] = r1;
}

extern "C" void kernel_launch(void* const* d_in, const int* in_sizes, int n_in,
                              void* d_out, int out_size, void* d_ws, size_t ws_size,
                              hipStream_t stream) {
    const float* xyz1 = (const float*)d_in[0];
    const float* xyz2 = (const float*)d_in[1];
    const float* p1   = (const float*)d_in[2];
    const float* p2   = (const float*)d_in[3];
    const float* W1   = (const float*)d_in[4];
    const float* g1   = (const float*)d_in[5];
    const float* be1  = (const float*)d_in[6];
    const float* W2   = (const float*)d_in[7];
    const float* g2   = (const float*)d_in[8];
    const float* be2  = (const float*)d_in[9];
    float* out = (float*)d_out;
    char* ws = (char*)d_ws;

    unsigned short* Xt  = (unsigned short*)(ws);                    // 50,331,648 B
    unsigned short* h1  = (unsigned short*)(ws + 50331648);         // 33,554,432 B
    unsigned short* h2  = (unsigned short*)(ws + 83886080);         // 33,554,432 B
    // p2t shares h2's slot: p2t lifetime (k_tr_p2 -> k_build) ends before h2 is written (GEMM2)
    unsigned short* p2t = (unsigned short*)(ws + 83886080);         // 8,388,608 B
    unsigned short* W1b = (unsigned short*)(ws + 117440512);        // 196,608 B
    unsigned short* W2b = (unsigned short*)(ws + 117637120);        // 131,072 B
    int*   idx3 = (int*)(ws + 117768192);                           // 786,432 B
    float* w3   = (float*)(ws + 118554624);                         // 786,432 B
    float* ps1  = (float*)(ws + 119341056);                         // 262,144 B
    float* pq1  = (float*)(ws + 119603200);                         // 262,144 B
    float* ps2  = (float*)(ws + 119865344);                         // 16,384 B
    float* pq2  = (float*)(ws + 119881728);                         // 16,384 B
    float* a1v  = (float*)(ws + 119898112);
    float* b1v  = (float*)(ws + 119899136);
    float* a2v  = (float*)(ws + 119900160);
    float* b2v  = (float*)(ws + 119901184);

    k_convert<<<dim3(384), dim3(256), 0, stream>>>(W1, W2, W1b, W2b);
    k_knn<<<dim3(64, 16), dim3(256), 0, stream>>>(xyz1, xyz2, idx3, w3);
    k_tr_p2<<<dim3(64, 16), dim3(256), 0, stream>>>(p2, p2t);
    k_build<<<dim3(128, 16), dim3(256), 0, stream>>>(p1, p2t, idx3, w3, Xt);
    // GEMM1: A = Xt (65536 x 384), B = W1b (256 x 384) -> h1[n][o]
    k_gemm<<<dim3(512, 2), dim3(256), 0, stream>>>(Xt, W1b, h1, 384, 256, 0);
    k_stats1<<<dim3(256), dim3(256), 0, stream>>>(h1, ps1, pq1);
    k_fin1<<<dim3(1), dim3(256), 0, stream>>>(ps1, pq1, g1, be1, a1v, b1v);
    k_norm1<<<dim3(8192), dim3(256), 0, stream>>>(h1, a1v, b1v);
    // GEMM2: A = W2b (256 x 256), B = h1 (65536 x 256) -> h2[b][o][n]
    k_gemm<<<dim3(2, 512), dim3(256), 0, stream>>>(W2b, h1, h2, 256, 4096, 1048576);
    k_stats2<<<dim3(4096), dim3(256), 0, stream>>>(h2, ps2, pq2);
    k_fin2<<<dim3(1), dim3(256), 0, stream>>>(ps2, pq2, g2, be2, a2v, b2v);
    k_final<<<dim3(8192), dim3(256), 0, stream>>>(h2, a2v, b2v, out);
}